// Round 3
// baseline (3866.429 us; speedup 1.0000x reference)
//
#include <hip/hip_runtime.h>

// ---------- types ----------
using bf16x8 = __attribute__((ext_vector_type(8))) __bf16;
using f32x4  = __attribute__((ext_vector_type(4))) float;

__device__ __forceinline__ f32x4 mfma16(bf16x8 a, bf16x8 b, f32x4 c) {
    return __builtin_amdgcn_mfma_f32_16x16x32_bf16(a, b, c, 0, 0, 0);
}

__device__ __forceinline__ bf16x8 cvt8v(float4 u, float4 v) {
    bf16x8 r;
    r[0] = (__bf16)u.x; r[1] = (__bf16)u.y; r[2] = (__bf16)u.z; r[3] = (__bf16)u.w;
    r[4] = (__bf16)v.x; r[5] = (__bf16)v.y; r[6] = (__bf16)v.z; r[7] = (__bf16)v.w;
    return r;
}

// ---------- constants ----------
#define HID   1024
#define B3    3072
#define NB    64
#define TENC  40
#define TDEC  27
#define TTOT  67      // TENC + TDEC
#define VOC   32000
#define HB    (NB * HID)
#define NBLK  128     // persistent grid

typedef const __attribute__((address_space(1))) void glb_cv;
typedef __attribute__((address_space(3))) void lds_v;

// ---------- init: zero h states + grid barrier counter ----------
__global__ __launch_bounds__(256) void init_state(__bf16* __restrict__ h1, __bf16* __restrict__ h2,
                                                  int* __restrict__ bar) {
    int i = blockIdx.x * 256 + threadIdx.x;   // 65536 threads
    h1[i] = (__bf16)0.f;
    h2[i] = (__bf16)0.f;
    if (i == 0) *bar = 0;
}

// ---------- f32 -> bf16 weight conversion (first 1<<logc cols of each row) ----------
__global__ __launch_bounds__(256) void cvt_w(const float* __restrict__ src, int ld, int logc,
                                             __bf16* __restrict__ dst, int n) {
    int i = blockIdx.x * 256 + threadIdx.x;
    if (i < n) {
        int row = i >> logc, col = i & ((1 << logc) - 1);
        dst[i] = (__bf16)src[(size_t)row * ld + col];
    }
}

// ---------- word gather ----------
__global__ __launch_bounds__(64) void gather_words(const float* __restrict__ emb,
                                                   const int* __restrict__ tgt,
                                                   __bf16* __restrict__ words) {
    int row = blockIdx.x;            // t*64 + b
    int b = row & 63, t = row >> 6;
    int idx = tgt[b * 28 + t];
    const float* src = emb + (size_t)idx * 512 + threadIdx.x * 8;
    float4 u = *(const float4*)src;
    float4 v = *(const float4*)(src + 4);
    *(bf16x8*)(words + (size_t)row * 512 + threadIdx.x * 8) = cvt8v(u, v);
}

// ---------- tiled 64x64 GEMM: C = A(MxK) @ B(NxK)^T + bias (for gi1 / wproj) ----------
template <typename TA>
__global__ __launch_bounds__(256) void gemm_bt(
    const TA* __restrict__ A, int lda,
    const float* __restrict__ Bw, int ldb,
    const float* __restrict__ bias,
    __bf16* __restrict__ Cout, int ldc,
    int K, int mdiv, int ms1, int ms2)
{
    __shared__ __align__(16) __bf16 As[64][40];
    __shared__ __align__(16) __bf16 Bs[64][40];
    const int tid  = threadIdx.x;
    const int m0   = blockIdx.x * 64;
    const int n0   = blockIdx.y * 64;
    const int srow = tid >> 2;
    const int sseg = (tid & 3) * 8;
    const TA*    ga = A  + (size_t)(m0 + srow) * lda + sseg;
    const float* gb = Bw + (size_t)(n0 + srow) * ldb + sseg;
    const int lane  = tid & 63, wave = tid >> 6;
    const int wm    = (wave >> 1) * 32, wn = (wave & 1) * 32;
    const int row15 = lane & 15, quad = lane >> 4;

    f32x4 acc[2][2] = {};
    for (int k = 0; k < K; k += 32) {
        __syncthreads();
        if constexpr (__is_same(TA, float)) {
            float4 u = *(const float4*)(ga + k);
            float4 v = *(const float4*)(ga + k + 4);
            *(bf16x8*)&As[srow][sseg] = cvt8v(u, v);
        } else {
            *(bf16x8*)&As[srow][sseg] = *(const bf16x8*)(ga + k);
        }
        {
            float4 u = *(const float4*)(gb + k);
            float4 v = *(const float4*)(gb + k + 4);
            *(bf16x8*)&Bs[srow][sseg] = cvt8v(u, v);
        }
        __syncthreads();
        bf16x8 a0 = *(const bf16x8*)&As[wm + row15][quad * 8];
        bf16x8 a1 = *(const bf16x8*)&As[wm + 16 + row15][quad * 8];
        bf16x8 b0 = *(const bf16x8*)&Bs[wn + row15][quad * 8];
        bf16x8 b1 = *(const bf16x8*)&Bs[wn + 16 + row15][quad * 8];
        acc[0][0] = mfma16(a0, b0, acc[0][0]);
        acc[0][1] = mfma16(a0, b1, acc[0][1]);
        acc[1][0] = mfma16(a1, b0, acc[1][0]);
        acc[1][1] = mfma16(a1, b1, acc[1][1]);
    }
    #pragma unroll
    for (int mt = 0; mt < 2; ++mt)
        #pragma unroll
        for (int nt = 0; nt < 2; ++nt)
            #pragma unroll
            for (int i = 0; i < 4; ++i) {
                int m = m0 + wm + mt * 16 + quad * 4 + i;
                int n = n0 + wn + nt * 16 + row15;
                int orow = (m % mdiv) * ms1 + (m / mdiv) * ms2;
                Cout[(size_t)orow * ldc + n] = (__bf16)(acc[mt][nt][i] + bias[n]);
            }
}

// ---------- hand-rolled grid barrier (device-scope) ----------
__device__ __forceinline__ void grid_barrier(int* bar, int target) {
    __syncthreads();
    if (threadIdx.x == 0) {
        __threadfence();                       // release: make writes visible device-wide
        atomicAdd(bar, 1);                     // device-scope by default on gfx950
        while (__hip_atomic_load(bar, __ATOMIC_RELAXED, __HIP_MEMORY_SCOPE_AGENT) < target) {}
        __threadfence();                       // acquire: invalidate stale cache
    }
    __syncthreads();
}

// ---------- persistent 2-layer GRU over all 67 steps ----------
// blocks 0..63: layer1 (ntile = blk); blocks 64..127: layer2 (ntile = blk-64)
// pipeline: iter p: L1 computes step p (p<67), L2 computes step p-1 (p>=1); 1 barrier/iter
__global__ __launch_bounds__(256, 1) void gru_persist(
    const __bf16* __restrict__ Whh1c, const float* __restrict__ bhh1, const float* __restrict__ bih1,
    const __bf16* __restrict__ Whh2c, const float* __restrict__ bhh2, const float* __restrict__ bih2,
    const __bf16* __restrict__ Wih2c,
    const __bf16* __restrict__ gi1,    // [40*64][3072] incl. bih1
    const __bf16* __restrict__ wproj,  // [27*64][3072] incl. bih2
    __bf16* __restrict__ h1b, __bf16* __restrict__ h2b,
    __bf16* __restrict__ h2all,
    int* __restrict__ bar)
{
    const int blk   = blockIdx.x;
    const bool isL2 = blk >= 64;
    const int ntile = isL2 ? blk - 64 : blk;
    const int lane  = threadIdx.x & 63;
    const int mtile = threadIdx.x >> 6;          // 4 waves = 4 batch-row tiles
    const int row15 = lane & 15, quad = lane >> 4;
    const int koff  = quad * 8;
    const int arow  = mtile * 16 + row15;
    const int brow  = ntile * 16 + row15;
    const int j     = ntile * 16 + row15;

    // weight row pointers (3 gate panels; +3 for layer2's Wih part)
    const __bf16 *w0, *w1, *w2, *u0, *u1, *u2;
    if (!isL2) {
        w0 = Whh1c + (size_t)(brow)           * HID + koff;
        w1 = Whh1c + (size_t)(brow + HID)     * HID + koff;
        w2 = Whh1c + (size_t)(brow + 2 * HID) * HID + koff;
        u0 = u1 = u2 = nullptr;
    } else {
        w0 = Whh2c + (size_t)(brow)           * HID + koff;
        w1 = Whh2c + (size_t)(brow + HID)     * HID + koff;
        w2 = Whh2c + (size_t)(brow + 2 * HID) * HID + koff;
        u0 = Wih2c + (size_t)(brow)           * HID + koff;
        u1 = Wih2c + (size_t)(brow + HID)     * HID + koff;
        u2 = Wih2c + (size_t)(brow + 2 * HID) * HID + koff;
    }

    for (int p = 0; p <= TTOT; ++p) {
        if (!isL2 && p < TTOT) {
            const int t = p;
            const __bf16* hprev = h1b + (p & 1) * HB;
            __bf16*       hout  = h1b + ((p + 1) & 1) * HB;
            const __bf16* ap = hprev + (size_t)arow * HID + koff;
            f32x4 ah0 = {}, ah1 = {}, ah2 = {};
            #pragma unroll 4
            for (int k = 0; k < HID; k += 32) {
                bf16x8 a = *(const bf16x8*)(ap + k);
                ah0 = mfma16(a, *(const bf16x8*)(w0 + k), ah0);
                ah1 = mfma16(a, *(const bf16x8*)(w1 + k), ah1);
                ah2 = mfma16(a, *(const bf16x8*)(w2 + k), ah2);
            }
            const float bh0 = bhh1[j], bh1v = bhh1[HID + j], bh2v = bhh1[2 * HID + j];
            #pragma unroll
            for (int i = 0; i < 4; ++i) {
                const int m = mtile * 16 + quad * 4 + i;
                float gir, giz, gin;
                if (t < TENC) {
                    const __bf16* pp = gi1 + (size_t)(t * NB + m) * B3 + j;
                    gir = (float)pp[0]; giz = (float)pp[HID]; gin = (float)pp[2 * HID];
                } else {
                    gir = bih1[j]; giz = bih1[HID + j]; gin = bih1[2 * HID + j];
                }
                float ghr = ah0[i] + bh0, ghz = ah1[i] + bh1v, ghn = ah2[i] + bh2v;
                float r = 1.f / (1.f + expf(-(gir + ghr)));
                float z = 1.f / (1.f + expf(-(giz + ghz)));
                float n = tanhf(gin + r * ghn);
                float ho = (float)hprev[(size_t)m * HID + j];
                hout[(size_t)m * HID + j] = (__bf16)((1.f - z) * n + z * ho);
            }
        } else if (isL2 && p >= 1) {
            const int t = p - 1;
            const __bf16* h2prev = h2b + ((p + 1) & 1) * HB;
            const __bf16* h1cur  = h1b + (p & 1) * HB;      // h1 after step t
            __bf16*       hout   = h2b + (p & 1) * HB;
            const __bf16* ap = h2prev + (size_t)arow * HID + koff;
            const __bf16* xp = h1cur  + (size_t)arow * HID + koff;
            f32x4 ah0 = {}, ah1 = {}, ah2 = {};
            f32x4 ai0 = {}, ai1 = {}, ai2 = {};
            #pragma unroll 4
            for (int k = 0; k < HID; k += 32) {
                bf16x8 a = *(const bf16x8*)(ap + k);
                ah0 = mfma16(a, *(const bf16x8*)(w0 + k), ah0);
                ah1 = mfma16(a, *(const bf16x8*)(w1 + k), ah1);
                ah2 = mfma16(a, *(const bf16x8*)(w2 + k), ah2);
                bf16x8 ax = *(const bf16x8*)(xp + k);
                ai0 = mfma16(ax, *(const bf16x8*)(u0 + k), ai0);
                ai1 = mfma16(ax, *(const bf16x8*)(u1 + k), ai1);
                ai2 = mfma16(ax, *(const bf16x8*)(u2 + k), ai2);
            }
            const float bh0 = bhh2[j], bh1v = bhh2[HID + j], bh2v = bhh2[2 * HID + j];
            #pragma unroll
            for (int i = 0; i < 4; ++i) {
                const int m = mtile * 16 + quad * 4 + i;
                float gir = ai0[i], giz = ai1[i], gin = ai2[i];
                if (t < TENC) {
                    gir += bih2[j]; giz += bih2[HID + j]; gin += bih2[2 * HID + j];
                } else {
                    const __bf16* pp = wproj + (size_t)((t - TENC) * NB + m) * B3 + j;
                    gir += (float)pp[0]; giz += (float)pp[HID]; gin += (float)pp[2 * HID];
                }
                float ghr = ah0[i] + bh0, ghz = ah1[i] + bh1v, ghn = ah2[i] + bh2v;
                float r = 1.f / (1.f + expf(-(gir + ghr)));
                float z = 1.f / (1.f + expf(-(giz + ghz)));
                float n = tanhf(gin + r * ghn);
                float ho = (float)h2prev[(size_t)m * HID + j];
                float hv = (1.f - z) * n + z * ho;
                hout[(size_t)m * HID + j] = (__bf16)hv;
                if (t >= TENC)
                    h2all[(size_t)(t - TENC) * HB + (size_t)m * HID + j] = (__bf16)hv;
            }
        }
        grid_barrier(bar, NBLK * (p + 1));
    }
}

// ---------- logits GEMM: 128x128 tile, A bf16 via global_load_lds, B f32 reg-cvt ----------
// C rows remapped: m = t*64+b -> orow = b*27+t; guard m < 1728
__global__ __launch_bounds__(256) void gemm128(
    const __bf16* __restrict__ A,     // h2all (reads up to row 1791, safe in ws)
    const float*  __restrict__ Bw,    // Wout 32000x1024 f32
    const float*  __restrict__ bias,
    float* __restrict__ C)
{
    __shared__ __align__(16) __bf16 As[128 * 32];
    __shared__ __align__(16) __bf16 Bs[128 * 32];
    const int tid  = threadIdx.x;
    const int wave = tid >> 6, lane = tid & 63;
    const int m0 = blockIdx.x * 128, n0 = blockIdx.y * 128;
    const int row15 = lane & 15, quad = lane >> 4;
    const int wm = (wave >> 1) * 64, wn = (wave & 1) * 64;

    // A async staging: wave w fills LDS chunks {2w,2w+1}; lane l -> chunk row l/4, col (l&3)*8
    const int ar0 = 2 * wave * 16 + (lane >> 2);
    const int ac  = (lane & 3) * 8;
    const __bf16* gA = A + (size_t)(m0 + ar0) * HID + ac;
    // B staging: thread t loads row t/2, 16-col half (t&1)
    const int brs = tid >> 1, bcs = (tid & 1) * 16;
    const float* gB = Bw + (size_t)(n0 + brs) * HID + bcs;

    f32x4 acc[4][4] = {};
    for (int k = 0; k < HID; k += 32) {
        float4 f0 = *(const float4*)(gB + k);
        float4 f1 = *(const float4*)(gB + k + 4);
        float4 f2 = *(const float4*)(gB + k + 8);
        float4 f3 = *(const float4*)(gB + k + 12);
        __syncthreads();
        __builtin_amdgcn_global_load_lds((glb_cv*)(gA + k),            (lds_v*)&As[(2 * wave)     * 512], 16, 0, 0);
        __builtin_amdgcn_global_load_lds((glb_cv*)(gA + k + 16 * HID), (lds_v*)&As[(2 * wave + 1) * 512], 16, 0, 0);
        *(bf16x8*)&Bs[brs * 32 + bcs]     = cvt8v(f0, f1);
        *(bf16x8*)&Bs[brs * 32 + bcs + 8] = cvt8v(f2, f3);
        __syncthreads();
        bf16x8 af[4], bf[4];
        #pragma unroll
        for (int mt = 0; mt < 4; ++mt) af[mt] = *(const bf16x8*)&As[(wm + mt * 16 + row15) * 32 + quad * 8];
        #pragma unroll
        for (int nt = 0; nt < 4; ++nt) bf[nt] = *(const bf16x8*)&Bs[(wn + nt * 16 + row15) * 32 + quad * 8];
        #pragma unroll
        for (int mt = 0; mt < 4; ++mt)
            #pragma unroll
            for (int nt = 0; nt < 4; ++nt)
                acc[mt][nt] = mfma16(af[mt], bf[nt], acc[mt][nt]);
    }
    #pragma unroll
    for (int mt = 0; mt < 4; ++mt) {
        const int mbase = m0 + wm + mt * 16 + quad * 4;
        #pragma unroll
        for (int nt = 0; nt < 4; ++nt) {
            const int n = n0 + wn + nt * 16 + row15;
            const float bv = bias[n];
            #pragma unroll
            for (int i = 0; i < 4; ++i) {
                const int m = mbase + i;
                if (m < TDEC * NB) {
                    const int orow = (m & 63) * TDEC + (m >> 6);
                    C[(size_t)orow * VOC + n] = acc[mt][nt][i] + bv;
                }
            }
        }
    }
}

// ---------- 2-pass row log-softmax (online logsumexp) ----------
__device__ __forceinline__ void lse_comb(float& m, float& s, float m2, float s2) {
    float nm = fmaxf(m, m2);
    s = s * expf(m - nm) + s2 * expf(m2 - nm);
    m = nm;
}

__global__ __launch_bounds__(256) void logsoftmax_rows(float* __restrict__ out) {
    const int r = blockIdx.x;
    float* p = out + (size_t)r * VOC;
    const int tid = threadIdx.x;
    const int lane = tid & 63, wid = tid >> 6;
    __shared__ float redm[4], reds[4];
    __shared__ float bc;

    float m = -3.0e38f, s = 0.f;
    for (int c = tid; c < VOC / 4; c += 256) {
        float4 v = ((const float4*)p)[c];
        float mx4 = fmaxf(fmaxf(v.x, v.y), fmaxf(v.z, v.w));
        float nm = fmaxf(m, mx4);
        s = s * expf(m - nm) + expf(v.x - nm) + expf(v.y - nm) + expf(v.z - nm) + expf(v.w - nm);
        m = nm;
    }
    #pragma unroll
    for (int o = 32; o > 0; o >>= 1) {
        float m2 = __shfl_down(m, o), s2 = __shfl_down(s, o);
        lse_comb(m, s, m2, s2);
    }
    if (lane == 0) { redm[wid] = m; reds[wid] = s; }
    __syncthreads();
    if (tid == 0) {
        float mm = redm[0], ss = reds[0];
        lse_comb(mm, ss, redm[1], reds[1]);
        lse_comb(mm, ss, redm[2], reds[2]);
        lse_comb(mm, ss, redm[3], reds[3]);
        bc = mm + logf(ss);
    }
    __syncthreads();
    const float Cst = bc;
    for (int c = tid; c < VOC / 4; c += 256) {
        float4 v = ((const float4*)p)[c];
        v.x -= Cst; v.y -= Cst; v.z -= Cst; v.w -= Cst;
        ((float4*)p)[c] = v;
    }
}

// ---------- launch ----------
extern "C" void kernel_launch(void* const* d_in, const int* in_sizes, int n_in,
                              void* d_out, int out_size, void* d_ws, size_t ws_size,
                              hipStream_t stream) {
    const float* vid  = (const float*)d_in[0];
    const int*   tgt  = (const int*)d_in[1];
    const float* emb  = (const float*)d_in[2];
    const float* Wih1 = (const float*)d_in[3];
    const float* Whh1 = (const float*)d_in[4];
    const float* bih1 = (const float*)d_in[5];
    const float* bhh1 = (const float*)d_in[6];
    const float* Wih2 = (const float*)d_in[7];
    const float* Whh2 = (const float*)d_in[8];
    const float* bih2 = (const float*)d_in[9];
    const float* bhh2 = (const float*)d_in[10];
    const float* Wout = (const float*)d_in[11];
    const float* bout = (const float*)d_in[12];
    float* out = (float*)d_out;

    char* w = (char*)d_ws;
    int*    bar   = (int*)w;    w += 256;
    __bf16* h1b   = (__bf16*)w; w += (size_t)2 * HB * 2;
    __bf16* h2b   = (__bf16*)w; w += (size_t)2 * HB * 2;
    __bf16* h2all = (__bf16*)w; w += (size_t)TDEC * HB * 2;
    __bf16* gi1   = (__bf16*)w; w += (size_t)TENC * NB * B3 * 2;
    __bf16* wproj = (__bf16*)w; w += (size_t)TDEC * NB * B3 * 2;
    __bf16* words = (__bf16*)w; w += (size_t)TDEC * NB * 512 * 2;
    __bf16* Whh1c = (__bf16*)w; w += (size_t)B3 * HID * 2;
    __bf16* Whh2c = (__bf16*)w; w += (size_t)B3 * HID * 2;
    __bf16* Wih2c = (__bf16*)w; w += (size_t)B3 * HID * 2;

    const int NW = B3 * HID;

    init_state<<<256, 256, 0, stream>>>(h1b, h2b, bar);
    cvt_w<<<(NW + 255) / 256, 256, 0, stream>>>(Whh1, 1024, 10, Whh1c, NW);
    cvt_w<<<(NW + 255) / 256, 256, 0, stream>>>(Whh2, 1024, 10, Whh2c, NW);
    cvt_w<<<(NW + 255) / 256, 256, 0, stream>>>(Wih2, 1536, 10, Wih2c, NW);

    // gi1[t*64+b] = vid[b][t] @ Wih1^T + bih1  (m=b*40+t -> orow=(m%40)*64+m/40)
    gemm_bt<float><<<dim3(TENC, 48), 256, 0, stream>>>(
        vid, 2048, Wih1, 2048, bih1, gi1, B3, 2048, TENC, 64, 1);

    gather_words<<<TDEC * NB, 64, 0, stream>>>(emb, tgt, words);

    // wproj[t*64+b] = words row @ Wih2[:,1024:]^T + bih2
    gemm_bt<__bf16><<<dim3(TDEC, 48), 256, 0, stream>>>(
        words, 512, Wih2 + 1024, 1536, bih2, wproj, B3, 512, 1 << 30, 1, 0);

    gru_persist<<<NBLK, 256, 0, stream>>>(Whh1c, bhh1, bih1, Whh2c, bhh2, bih2, Wih2c,
                                          gi1, wproj, h1b, h2b, h2all, bar);

    gemm128<<<dim3(14, VOC / 128), 256, 0, stream>>>(h2all, Wout, bout, out);

    logsoftmax_rows<<<TDEC * NB, 256, 0, stream>>>(out);
}